// Round 5
// baseline (1003.555 us; speedup 1.0000x reference)
//
#include <hip/hip_runtime.h>

// ResidualConvLSTM2D on MI355X (gfx950).
// Fused per-timestep implicit GEMM: z = conv3x3([x_t || h_{t-1}], [Wx || Wh]) via
// bf16 MFMA (16x16x32), fp32 LSTM cell, fp32 residual 1x1 conv.
//
// R5: barrier-free K-loop. R3/R4 showed the per-K-step __syncthreads (with its
// compiler-forced vmcnt(0) drain) is the bottleneck (MfmaUtil 5% at any
// occupancy). Weights are L2-resident (442 KB) -> each wave loads its own
// B-fragments global->VGPR directly from a fragment-ordered image WT2[n'][864]
// (1-deep register rotation); A-patch staged to LDS ONCE. K-loop has NO
// barriers; per-wave waitcnts only. 512 blocks x 256 thr, 37 KB LDS,
// launch_bounds(256,4) -> 4 blocks/CU, 16 waves/CU.
// Column order n' = fb*128 + gate*32 + fi (f = fb*32+fi): each block owns
// 32 f-channels x all 4 gates -> LSTM cell stays block-local; wave w = gate w.
//
// ws layout (4.65 MB):
//   [0, 442368)        WT2 bf16 [256][864]  (fragment-ordered, k-major rows)
//   [557056, +2MB)     h ping  bf16 [4][64][64][64]
//   [2654208, +2MB)    h pong  bf16
// Cell state c (fp32) lives inside d_out: c_t at out[b][t][...] (read before
// that address is overwritten with the output), c_{t+1} into slab t+1.
#define B_ 4
#define T_ 16
#define H_ 64
#define W_ 64
#define CIN 32
#define F_ 64
#define NCH 256
#define KTOT 864
#define KSTEPS 27
#define TSLAB (H_ * W_ * F_)   // 262144 floats between (b,t) and (b,t+1)

#define OFF_H0 557056
#define OFF_H1 2654208

typedef __attribute__((ext_vector_type(8))) short short8;
typedef __attribute__((ext_vector_type(4))) float floatx4;

__device__ __forceinline__ unsigned short f2bf(float f) {
  union { float f; unsigned u; } v; v.f = f;
  unsigned r = v.u + 0x7FFFu + ((v.u >> 16) & 1u);   // round-to-nearest-even
  return (unsigned short)(r >> 16);
}

// tanh via hardware exp2; saturates correctly for |z| large.
__device__ __forceinline__ float tanh_fast(float z) {
  float e = __expf(2.0f * z);
  return 1.0f - 2.0f * __builtin_amdgcn_rcpf(e + 1.0f);
}

// WT2[n'][k] bf16, k-major. n' = fb*128 + g*32 + fi; f = fb*32+fi; orig
// n = g*64 + f. k = tap*96 + ch; ch<32 -> Wx, else Wh.
__global__ void prep_weights(const float* __restrict__ Wx, const float* __restrict__ Wh,
                             unsigned short* __restrict__ WT2) {
  int idx = blockIdx.x * 256 + threadIdx.x;            // 0..221183
  int np = idx / KTOT;
  int k  = idx - np * KTOT;
  int fb = np >> 7, g = (np >> 5) & 3, fi = np & 31;
  int n  = g * 64 + fb * 32 + fi;
  int tap = k / 96;
  int ch  = k - tap * 96;
  float f = (ch < CIN) ? Wx[(tap * CIN + ch) * NCH + n]
                       : Wh[(tap * F_ + (ch - CIN)) * NCH + n];
  WT2[idx] = f2bf(f);
}

// Zero h ping+pong (4 MB in ws).
__global__ void prep_zero_h(float4* __restrict__ p) {
  int idx = blockIdx.x * 256 + threadIdx.x;
  p[idx] = make_float4(0.f, 0.f, 0.f, 0.f);
}

// Zero c0 = out slabs [b][0][...].
__global__ void prep_zero_c(float* __restrict__ out) {
  int idx = blockIdx.x * 256 + threadIdx.x;            // float4 units
  int b = idx >> 16;
  int i = idx & 65535;
  ((float4*)(out + (size_t)b * (T_ * TSLAB)))[i] = make_float4(0.f, 0.f, 0.f, 0.f);
}

__global__ __launch_bounds__(256, 4)
void step_kernel(const float* __restrict__ x, const float* __restrict__ bias,
                 const float* __restrict__ Wp, const float* __restrict__ bp,
                 const unsigned short* __restrict__ WT2,
                 const unsigned short* __restrict__ hprev,
                 unsigned short* __restrict__ hnew,
                 float* __restrict__ out, int t)
{
  // LDS: patch [136][104] sh (28288 B). Epilogue overlay: gact [64][130] fp32
  // (33280 B) @0, WpL [32][32] fp32 (4096 B) @33280. Total 37376 B.
  __shared__ __align__(16) char smem[37376];
  short* patch = (short*)smem;
  float* gact  = (float*)smem;
  float* WpL   = (float*)(smem + 33280);

  const int tid  = threadIdx.x;
  const int w    = tid >> 6;          // wave = gate
  const int lane = tid & 63;
  const int quad = lane >> 4;
  const int lr   = lane & 15;

  const int bid = blockIdx.x;
  const int fb  = bid & 1;            // f-half (32 channels x 4 gates)
  const int mt  = bid >> 1;
  const int b   = mt >> 6;
  const int r   = mt & 63;
  const int y0  = (r >> 1) << 1;      // 2-row tile
  const int x0  = (r & 1) << 5;       // 32-col half

  // ---- per-lane B pointers (fragment-ordered image: lane addr IS frag addr)
  const unsigned short* wp0 = WT2 + (fb * 128 + w * 32 + lr) * KTOT + quad * 8;
  const unsigned short* wp1 = wp0 + 16 * KTOT;

  // prefetch s=0 B-frags (global->VGPR, in flight during patch staging)
  short8 bcur0 = *(const short8*)(wp0);
  short8 bcur1 = *(const short8*)(wp1);

  // ---- stage input patch once: 4 rows x 34 cols x 96 ch (x bf16 | h bf16)
  if (tid < 136) {
    int sy = tid / 34, sx = tid - sy * 34;
    int yy = y0 + sy - 1, xx = x0 + sx - 1;
    short* dst = patch + tid * 104;
    if (yy >= 0 && yy < H_ && xx >= 0 && xx < W_) {
      const float4* xs = (const float4*)(x + ((((b * T_ + t) * H_ + yy) * W_ + xx) * CIN));
      #pragma unroll
      for (int j = 0; j < 4; j++) {
        float4 f0 = xs[2 * j];
        float4 f1 = xs[2 * j + 1];
        union { short8 v; unsigned short u[8]; } pk;
        pk.u[0] = f2bf(f0.x); pk.u[1] = f2bf(f0.y); pk.u[2] = f2bf(f0.z); pk.u[3] = f2bf(f0.w);
        pk.u[4] = f2bf(f1.x); pk.u[5] = f2bf(f1.y); pk.u[6] = f2bf(f1.z); pk.u[7] = f2bf(f1.w);
        ((short8*)dst)[j] = pk.v;
      }
      const uint4* hs = (const uint4*)(hprev + ((b * H_ + yy) * W_ + xx) * F_);
      uint4* d2 = (uint4*)(dst + 32);
      #pragma unroll
      for (int j = 0; j < 8; j++) d2[j] = hs[j];
    } else {
      uint4 z = make_uint4(0, 0, 0, 0);
      uint4* d4 = (uint4*)dst;
      #pragma unroll
      for (int j = 0; j < 12; j++) d4[j] = z;
    }
  }

  float bias_r[2];
  #pragma unroll
  for (int nf = 0; nf < 2; nf++) bias_r[nf] = bias[w * 64 + fb * 32 + nf * 16 + lr];

  // A lane offsets per m-frag (shorts)
  int paoff[4];
  #pragma unroll
  for (int mf = 0; mf < 4; mf++) {
    int p = mf * 16 + lr;
    paoff[mf] = ((p >> 5) * 34 + (p & 31)) * 104 + quad * 8;
  }

  floatx4 acc[4][2];
  #pragma unroll
  for (int mf = 0; mf < 4; mf++)
    #pragma unroll
    for (int nf = 0; nf < 2; nf++)
      acc[mf][nf] = (floatx4){0.f, 0.f, 0.f, 0.f};

  __syncthreads();   // patch visible; the ONLY barrier before the epilogue

  // ---- K loop: 27 steps of BK=32, fully unrolled, NO barriers.
  //      B-frags: global->VGPR with 1-deep rotation; A-frags: LDS (read-only).
  #pragma unroll
  for (int s = 0; s < KSTEPS; s++) {
    short8 bnx0, bnx1;
    if (s < KSTEPS - 1) {
      bnx0 = *(const short8*)(wp0 + (s + 1) * 32);
      bnx1 = *(const short8*)(wp1 + (s + 1) * 32);
    }
    const int g  = s / 3;
    const int c0 = (s - g * 3) * 32;
    const int koff = ((g / 3) * 34 + (g % 3)) * 104 + c0;   // compile-time
    short8 afr[4];
    #pragma unroll
    for (int mf = 0; mf < 4; mf++)
      afr[mf] = *(const short8*)(patch + paoff[mf] + koff);
    #pragma unroll
    for (int mf = 0; mf < 4; mf++) {
      acc[mf][0] = __builtin_amdgcn_mfma_f32_16x16x32_bf16(afr[mf], bcur0, acc[mf][0], 0, 0, 0);
      acc[mf][1] = __builtin_amdgcn_mfma_f32_16x16x32_bf16(afr[mf], bcur1, acc[mf][1], 0, 0, 0);
    }
    bcur0 = bnx0;
    bcur1 = bnx1;
  }

  __syncthreads();   // all waves done reading patch (gact overlays it)

  // ---- epilogue: activations -> gact[p*130 + n'loc] (2-way banks on writes)
  #pragma unroll
  for (int mf = 0; mf < 4; mf++)
    #pragma unroll
    for (int nf = 0; nf < 2; nf++)
      #pragma unroll
      for (int rr = 0; rr < 4; rr++) {
        int p = mf * 16 + quad * 4 + rr;          // D row = quad*4 + reg
        float z = acc[mf][nf][rr] + bias_r[nf];
        float a;
        if (w == 2) a = tanh_fast(z);             // candidate gate (wave-uniform)
        else {                                    // hard_sigmoid for i, f, o
          a = __builtin_fmaf(z, 0.2f, 0.5f);
          a = fminf(fmaxf(a, 0.f), 1.f);
        }
        gact[p * 130 + w * 32 + nf * 16 + lr] = a;
      }
  {                                               // Wp fb-half -> LDS [32ci][32f]
    ((float4*)WpL)[tid] = *(const float4*)(Wp + (tid >> 3) * 64 + fb * 32 + (tid & 7) * 4);
  }

  const int p   = tid >> 2;                       // pixel 0..63
  const int fh  = tid & 3;                        // f-octet within the 32-f half
  const int fl  = fh * 8;
  const int cb  = fb * 32 + fl;                   // global channel base
  const int gy  = y0 + (p >> 5), gx = x0 + (p & 31);
  const int hbase   = ((b * H_ + gy) * W_ + gx) * F_ + cb;
  const int outbase = (((b * T_ + t) * H_ + gy) * W_ + gx) * F_ + cb;

  // prefetch x (residual) and c_t (global) before the barrier
  float xv[32];
  {
    const float4* xs = (const float4*)(x + ((((b * T_ + t) * H_ + gy) * W_ + gx) * CIN));
    #pragma unroll
    for (int j = 0; j < 8; j++) {
      float4 f = xs[j];
      xv[4 * j] = f.x; xv[4 * j + 1] = f.y; xv[4 * j + 2] = f.z; xv[4 * j + 3] = f.w;
    }
  }
  float4 co4[2];
  #pragma unroll
  for (int j = 0; j < 2; j++) co4[j] = *(const float4*)(out + outbase + 4 * j);

  __syncthreads();                                // gact + WpL visible

  // ---- residual 1x1 conv (fp32): 8 output channels per thread
  float res[8];
  #pragma unroll
  for (int j = 0; j < 8; j++) res[j] = bp[cb + j];
  for (int ci = 0; ci < 32; ci++) {
    float xf = xv[ci];
    #pragma unroll
    for (int j4 = 0; j4 < 2; j4++) {
      float4 wv = *(const float4*)(WpL + ci * 32 + fl + j4 * 4);
      res[j4 * 4 + 0] += xf * wv.x;
      res[j4 * 4 + 1] += xf * wv.y;
      res[j4 * 4 + 2] += xf * wv.z;
      res[j4 * 4 + 3] += xf * wv.w;
    }
  }

  // ---- LSTM cell combine: gates at gact[p*130 + g*32 + fl+j]
  float iv[8], fv[8], gv[8], ov[8];
  #pragma unroll
  for (int j4 = 0; j4 < 2; j4++) {
    float4 a0 = *(const float4*)(gact + p * 130 +  0 + fl + j4 * 4);
    float4 a1 = *(const float4*)(gact + p * 130 + 32 + fl + j4 * 4);
    float4 a2 = *(const float4*)(gact + p * 130 + 64 + fl + j4 * 4);
    float4 a3 = *(const float4*)(gact + p * 130 + 96 + fl + j4 * 4);
    iv[j4*4+0]=a0.x; iv[j4*4+1]=a0.y; iv[j4*4+2]=a0.z; iv[j4*4+3]=a0.w;
    fv[j4*4+0]=a1.x; fv[j4*4+1]=a1.y; fv[j4*4+2]=a1.z; fv[j4*4+3]=a1.w;
    gv[j4*4+0]=a2.x; gv[j4*4+1]=a2.y; gv[j4*4+2]=a2.z; gv[j4*4+3]=a2.w;
    ov[j4*4+0]=a3.x; ov[j4*4+1]=a3.y; ov[j4*4+2]=a3.z; ov[j4*4+3]=a3.w;
  }
  union { unsigned short hv[8]; uint4 q; } hu;
  #pragma unroll
  for (int j4 = 0; j4 < 2; j4++) {
    float cold[4] = {j4 ? co4[1].x : co4[0].x, j4 ? co4[1].y : co4[0].y,
                     j4 ? co4[1].z : co4[0].z, j4 ? co4[1].w : co4[0].w};
    float cn4[4], h4[4];
    #pragma unroll
    for (int e = 0; e < 4; e++) {
      int j = j4 * 4 + e;
      float cn = fv[j] * cold[e] + iv[j] * gv[j];
      float h  = ov[j] * tanh_fast(cn);
      cn4[e] = cn; h4[e] = h;
      hu.hv[j] = f2bf(h);
    }
    if (t < T_ - 1)                               // c_{t+1} -> next out slab
      *(float4*)(out + outbase + TSLAB + j4 * 4) = make_float4(cn4[0], cn4[1], cn4[2], cn4[3]);
    *(float4*)(out + outbase + j4 * 4) = make_float4(h4[0] + res[j4 * 4 + 0], h4[1] + res[j4 * 4 + 1],
                                                     h4[2] + res[j4 * 4 + 2], h4[3] + res[j4 * 4 + 3]);
  }
  *(uint4*)(hnew + hbase) = hu.q;
}

extern "C" void kernel_launch(void* const* d_in, const int* in_sizes, int n_in,
                              void* d_out, int out_size, void* d_ws, size_t ws_size,
                              hipStream_t stream) {
  const float* x    = (const float*)d_in[0];
  const float* Wx   = (const float*)d_in[1];
  const float* Wh   = (const float*)d_in[2];
  const float* bias = (const float*)d_in[3];
  const float* Wp   = (const float*)d_in[4];
  const float* bp   = (const float*)d_in[5];
  float* out = (float*)d_out;

  unsigned short* WT2 = (unsigned short*)d_ws;
  unsigned short* h0  = (unsigned short*)((char*)d_ws + OFF_H0);
  unsigned short* h1  = (unsigned short*)((char*)d_ws + OFF_H1);

  hipLaunchKernelGGL(prep_weights, dim3(864), dim3(256), 0, stream, Wx, Wh, WT2);
  hipLaunchKernelGGL(prep_zero_h, dim3(1024), dim3(256), 0, stream,
                     (float4*)((char*)d_ws + OFF_H0));
  hipLaunchKernelGGL(prep_zero_c, dim3(1024), dim3(256), 0, stream, out);

  for (int t = 0; t < T_; t++) {
    const unsigned short* hp = (t & 1) ? h1 : h0;
    unsigned short*       hn = (t & 1) ? h0 : h1;
    hipLaunchKernelGGL(step_kernel, dim3(512), dim3(256), 0, stream,
                       x, bias, Wp, bp, WT2, hp, hn, out, t);
  }
}